// Round 7
// baseline (204.309 us; speedup 1.0000x reference)
//
#include <hip/hip_runtime.h>
#include <hip/hip_bf16.h>

typedef __bf16 bf16x8 __attribute__((ext_vector_type(8)));
typedef short s16x4 __attribute__((ext_vector_type(4)));
typedef float f32x4 __attribute__((ext_vector_type(4)));
typedef unsigned short u16x8 __attribute__((ext_vector_type(8)));

#define MFMA_K32(a, b, c) __builtin_amdgcn_mfma_f32_16x16x32_bf16(a, b, c, 0, 0, 0)

// 16x16x16 bf16 MFMA; builtin exists only in device pass.
static __device__ __forceinline__ f32x4 mfma_k16(s16x4 a, s16x4 b, f32x4 c) {
#ifdef __HIP_DEVICE_COMPILE__
    return __builtin_amdgcn_mfma_f32_16x16x16bf16_1k(a, b, c, 0, 0, 0);
#else
    return c;
#endif
}

static __device__ __forceinline__ float fast_exp2(float x) {
#ifdef __HIP_DEVICE_COMPILE__
    return __builtin_amdgcn_exp2f(x);
#else
    return x;
#endif
}

static __device__ __forceinline__ void prio_hi() {
#ifdef __HIP_DEVICE_COMPILE__
    __builtin_amdgcn_s_setprio(1);
#endif
}
static __device__ __forceinline__ void prio_lo() {
#ifdef __HIP_DEVICE_COMPILE__
    __builtin_amdgcn_s_setprio(0);
#endif
}

// async global->LDS, 16B per lane; lds dest = wave-uniform base + lane*16
#define GLL16(gp, lp)                                              \
    __builtin_amdgcn_global_load_lds(                              \
        (const __attribute__((address_space(1))) void*)(gp),       \
        (__attribute__((address_space(3))) void*)(lp), 16, 0, 0)

// round-to-nearest-even fp32 -> bf16 (finite inputs only)
static __device__ __forceinline__ unsigned short f2bf(float f) {
    unsigned int u = __float_as_uint(f);
    u += 0x7fffu + ((u >> 16) & 1u);
    return (unsigned short)(u >> 16);
}

// packed fp32x2 -> bf16x2 (RNE) via gfx950 v_cvt_pk_bf16_f32 when available
static __device__ __forceinline__ unsigned int cvtpk_bf16(float lo, float hi) {
#if defined(__HIP_DEVICE_COMPILE__) && __has_builtin(__builtin_amdgcn_cvt_pk_bf16_f32)
    typedef __bf16 bf16x2 __attribute__((ext_vector_type(2)));
    bf16x2 r = __builtin_amdgcn_cvt_pk_bf16_f32(lo, hi);
    return __builtin_bit_cast(unsigned int, r);
#else
    return (unsigned int)f2bf(lo) | ((unsigned int)f2bf(hi) << 16);
#endif
}

#define LOG2E 1.44269504088896340736f

// ---------------------------------------------------------------------------
// Fused prep: transpose+cast w_qkv and w_out, rmsnorm x -> xn (bf16).
// bid < 3072: w_qkv tile; < 4096: w_out tile; else rmsnorm row (bid-4096).
// ---------------------------------------------------------------------------
__global__ __launch_bounds__(256) void prep_k(
    const float* __restrict__ x, const float* __restrict__ gamma,
    const float* __restrict__ w_qkv, const float* __restrict__ w_out,
    unsigned short* __restrict__ xn, unsigned short* __restrict__ wtq,
    unsigned short* __restrict__ wto) {
    __shared__ float sm[32][33];
    int bid = blockIdx.x, tid = threadIdx.x;
    if (bid < 4096) {  // transpose paths (block-uniform branch)
        const float* in;
        unsigned short* out;
        int R = 1024, C, bx, by;
        if (bid < 3072) { in = w_qkv; out = wtq; C = 3072; bx = bid % 96; by = bid / 96; }
        else { int b2 = bid - 3072; in = w_out; out = wto; C = 1024; bx = b2 % 32; by = b2 / 32; }
        int c0 = bx * 32, r0 = by * 32;
        int tr = tid >> 5, tc = tid & 31;
#pragma unroll
        for (int i = 0; i < 4; i++)
            sm[tr + i * 8][tc] = in[(size_t)(r0 + tr + i * 8) * C + c0 + tc];
        __syncthreads();
#pragma unroll
        for (int i = 0; i < 4; i++)
            out[(size_t)(c0 + tr + i * 8) * R + r0 + tc] = f2bf(sm[tc][tr + i * 8]);
    } else {  // rmsnorm
        int row = bid - 4096;
        const float* xr = x + (size_t)row * 1024;
        float4 v = *(const float4*)(xr + tid * 4);
        float ss = v.x * v.x + v.y * v.y + v.z * v.z + v.w * v.w;
#pragma unroll
        for (int off = 1; off < 64; off <<= 1) ss += __shfl_xor(ss, off, 64);
        if ((tid & 63) == 0) sm[0][tid >> 6] = ss;
        __syncthreads();
        float tot = sm[0][0] + sm[0][1] + sm[0][2] + sm[0][3];
        float f = 32.0f / fmaxf(sqrtf(tot), 1e-12f);  // sqrt(1024)=32
        float4 g = *(const float4*)(gamma + tid * 4);
        uint2 o;
        o.x = cvtpk_bf16(v.x * f * g.x, v.y * f * g.y);
        o.y = cvtpk_bf16(v.z * f * g.z, v.w * f * g.w);
        *(uint2*)(xn + (size_t)row * 1024 + tid * 4) = o;
    }
}

// ---------------------------------------------------------------------------
// GEMM (m97 structure): C[M,N] = A[M,K] * BT[N,K]^T, bf16 in, fp32 acc.
// BM x 128 tile, BK=32, global_load_lds width-16 staging into unpadded LDS.
// BM=128: 4 waves 2x2 (4x4 frags). BM=64: 4 waves 1x4 (4x2 frags).
// MODE 0: fp32 store (atomicAdd when KS>1). MODE 1: qkv epilogue.
// R5 lesson: BM=128 on the 4096x1024 GEMM -> 256 blocks = 1 block/CU; the
// m97 structure needs >=2 co-resident blocks to cover its barrier drain.
// R6 lesson: gemm2 at 2 blocks/CU runs ~735 ns/block-step vs m97's ~307 at
// 4 blocks/CU -> per-step cost is stall-dominated and drops with TLP.
// KS (split-K): blockIdx.z picks a K/KS chunk; MODE-0 epilogue atomicAdds
// into pre-zeroed C. 1024 blocks = 4/CU for gemm2.
// ---------------------------------------------------------------------------
template <int MODE, int BM, int KS>
__global__ __launch_bounds__(256) void gemm_bt_k(
    const unsigned short* __restrict__ A, const unsigned short* __restrict__ BT,
    float* __restrict__ C, unsigned short* __restrict__ qw,
    unsigned short* __restrict__ kw, unsigned short* __restrict__ vw,
    int M, int N, int K) {
    constexpr int RT = 4;
    constexpr int CT = (BM == 128) ? 4 : 2;
    __shared__ unsigned short As[BM][32];
    __shared__ unsigned short Bs[128][32];
    int tid = threadIdx.x;
    int wave = tid >> 6, lane = tid & 63, quad = lane >> 4, l16 = lane & 15;
    int wrb, wcb;
    if constexpr (BM == 128) { wrb = (wave >> 1) * 64; wcb = (wave & 1) * 64; }
    else { wrb = 0; wcb = wave * 32; }
    int m0 = blockIdx.y * BM, n0 = blockIdx.x * 128;
    int k_beg = 0, k_end = K;
    if constexpr (KS > 1) {
        int kz = blockIdx.z;
        k_beg = kz * (K / KS);
        k_end = k_beg + K / KS;
    }
    int lrow = lane >> 2, lcol = (lane & 3) * 8;  // lane -> (row,col) in 16x32 chunk
    const unsigned short *Ag0, *Ag1 = nullptr;
    if constexpr (BM == 128) {
        Ag0 = A + (size_t)(m0 + wave * 32 + lrow) * K + lcol;
        Ag1 = A + (size_t)(m0 + wave * 32 + 16 + lrow) * K + lcol;
    } else {
        Ag0 = A + (size_t)(m0 + wave * 16 + lrow) * K + lcol;
    }
    const unsigned short* Bg0 = BT + (size_t)(n0 + wave * 32 + lrow) * K + lcol;
    const unsigned short* Bg1 = BT + (size_t)(n0 + wave * 32 + 16 + lrow) * K + lcol;
    f32x4 acc[RT][CT] = {};
    for (int k0 = k_beg; k0 < k_end; k0 += 32) {
        __syncthreads();  // prior ds_reads done before overwrite
        if constexpr (BM == 128) {
            GLL16(Ag0 + k0, &As[wave * 32][0]);
            GLL16(Ag1 + k0, &As[wave * 32 + 16][0]);
        } else {
            GLL16(Ag0 + k0, &As[wave * 16][0]);
        }
        GLL16(Bg0 + k0, &Bs[wave * 32][0]);
        GLL16(Bg1 + k0, &Bs[wave * 32 + 16][0]);
        __syncthreads();  // drains vmcnt: staging complete
        bf16x8 af[RT], bfr[CT];
#pragma unroll
        for (int t = 0; t < RT; t++)
            af[t] = *(const bf16x8*)&As[wrb + t * 16 + l16][quad * 8];
#pragma unroll
        for (int t = 0; t < CT; t++)
            bfr[t] = *(const bf16x8*)&Bs[wcb + t * 16 + l16][quad * 8];
#pragma unroll
        for (int rt = 0; rt < RT; rt++)
#pragma unroll
            for (int ct = 0; ct < CT; ct++)
                acc[rt][ct] = MFMA_K32(af[rt], bfr[ct], acc[rt][ct]);
    }
#pragma unroll
    for (int rt = 0; rt < RT; rt++) {
        int mb = m0 + wrb + rt * 16 + quad * 4;
        int b = mb >> 11, nn = mb & 2047;
#pragma unroll
        for (int ct = 0; ct < CT; ct++) {
            int col = n0 + wcb + ct * 16 + l16;
            if (MODE == 0) {
                if constexpr (KS > 1) {
#pragma unroll
                    for (int r = 0; r < 4; r++)
                        atomicAdd(&C[(size_t)(mb + r) * N + col], acc[rt][ct][r]);
                } else {
#pragma unroll
                    for (int r = 0; r < 4; r++)
                        C[(size_t)(mb + r) * N + col] = acc[rt][ct][r];
                }
            } else {
                int sec = col >> 10, ci = col & 1023;
                int hh = ci >> 6, dd = ci & 63;
                int bh = b * 16 + hh;
                if (sec == 0) {
#pragma unroll
                    for (int r = 0; r < 4; r++)
                        qw[((size_t)bh * 2048 + nn + r) * 64 + dd] =
                            f2bf(acc[rt][ct][r] * (0.125f * LOG2E));
                } else if (sec == 1) {
#pragma unroll
                    for (int r = 0; r < 4; r++)
                        kw[((size_t)bh * 2048 + nn + r) * 64 + dd] = f2bf(acc[rt][ct][r]);
                } else {
                    uint2 pk;
                    pk.x = cvtpk_bf16(acc[rt][ct][0], acc[rt][ct][1]);
                    pk.y = cvtpk_bf16(acc[rt][ct][2], acc[rt][ct][3]);
                    *(uint2*)&vw[((size_t)bh * 64 + dd) * 2048 + nn] = pk;
                }
            }
        }
    }
}

// ---------------------------------------------------------------------------
// Causal flash attention, key-split 8-wave blocks (R6 structure, UNCHANGED).
// R6 validated the chain-cut softmax: 53 -> 46.7us, matching prediction.
//   Per-lane max in the common path; wave-uniform __any(mx_l > mrun+8)
//   ballot gates the full reduce+rescale (rare); P bounded by 2^8 (T13).
//   lrun is a per-lane partial reduced once in the epilogue.
// Groups of 4 waves process key ranges [0,qt+1) / [qt+1,2qt+2) of 32-key
// tiles; merge via LDS (fully-masked rows killed by a1 -> 0).
// (512,4): 128-reg budget, no spill (R1 lesson).
// ---------------------------------------------------------------------------
__global__ __launch_bounds__(512, 4) void attn_k(
    const unsigned short* __restrict__ q, const unsigned short* __restrict__ k,
    const unsigned short* __restrict__ vt, unsigned short* __restrict__ o) {
    // LDS union: [group][buf] K tiles (32x64, pad 72) + V tiles (64x32, pad 40);
    // epilogue overlays Osm[64][68] f32 on the K region, msm/lsm on V region.
    __shared__ __align__(16) char smem[38912];
    typedef unsigned short ush;
    ush(*Ks)[2][32][72] = (ush(*)[2][32][72])smem;            // 18432 B
    ush(*Vt)[2][64][40] = (ush(*)[2][64][40])(smem + 18432);  // 20480 B
    float(*Osm)[68] = (float(*)[68])smem;                     // 17408 B (<= K region)
    float* msm = (float*)(smem + 18432);                      // 256 B (in V region)
    float* lsm = msm + 64;

    int bh = blockIdx.x;
    int qt = 31 - (int)blockIdx.y;  // heavy-first LPT order
    int tid = threadIdx.x, wave = tid >> 6, lane = tid & 63;
    int quad = lane >> 4, l16 = lane & 15;
    int g = wave >> 2, wq = wave & 3;
    int b = bh >> 4, h = bh & 15;
    const ush* qg = q + (size_t)bh * 2048 * 64;
    const ush* kg = k + (size_t)bh * 2048 * 64;
    const ush* vg = vt + (size_t)bh * 64 * 2048;

    // staging map: 256 threads/group; K: 32 rows x 64 cols; V: 64 d x 32 keys
    int ti = wq * 64 + lane;
    int kr = ti >> 3, kc = (ti & 7) * 8;
    int vr = ti >> 2, vc = (ti & 3) * 8;
    const ush* Kg = kg + (size_t)kr * 64 + kc;
    const ush* Vg = vg + (size_t)vr * 2048 + vc;

    int row_l = wq * 16 + l16;    // local q row 0..63
    int q0w = qt * 64 + wq * 16;  // global q row base for this wave
    bf16x8 bq[2];                 // Q^T B-operand: [k=d=ks*32+quad*8+j][n=qrow=l16]
#pragma unroll
    for (int ks = 0; ks < 2; ks++)
        bq[ks] = *(const bf16x8*)&qg[(size_t)(q0w + l16) * 64 + ks * 32 + quad * 8];

    f32x4 ot[4] = {};                 // Ot C-layout: [d=dt*16+quad*4+r][qrow=l16]
    float mrun = -1e30f, lrun = 0.f;  // lrun is a PER-LANE partial (reduced at end)
    int nT = qt + 1;                  // tiles per group (equal for both groups)
    int kt0 = g ? (qt + 1) : 0;

    u16x8 pk, pv;  // prefetch registers
    // preload first tile into buf 0
    pk = *(const u16x8*)(Kg + (size_t)kt0 * 2048);
    pv = *(const u16x8*)(Vg + kt0 * 32);
    *(u16x8*)&Ks[g][0][kr][kc] = pk;
    *(u16x8*)&Vt[g][0][vr][vc] = pv;
    __syncthreads();

    for (int i = 0; i < nT; i++) {
        int cb = i & 1, kt = kt0 + i;
        bool pf = (i + 1 < nT);
        if (pf) {  // issue next tile's global loads early (wave-uniform branch)
            pk = *(const u16x8*)(Kg + (size_t)(kt + 1) * 2048);
            pv = *(const u16x8*)(Vg + (kt + 1) * 32);
        }
        // St[key=ct*16+quad*4+r][qrow=l16] = K . Q^T
        f32x4 sf[2];
        prio_hi();
#pragma unroll
        for (int ct = 0; ct < 2; ct++) {
            bf16x8 ak0 = *(const bf16x8*)&Ks[g][cb][ct * 16 + l16][quad * 8];
            bf16x8 ak1 = *(const bf16x8*)&Ks[g][cb][ct * 16 + l16][32 + quad * 8];
            f32x4 s = {};
            s = MFMA_K32(ak0, bq[0], s);
            s = MFMA_K32(ak1, bq[1], s);
            sf[ct] = s;
        }
        prio_lo();
        if (kt >= 2 * qt) {  // tiles that can touch the diagonal
#pragma unroll
            for (int ct = 0; ct < 2; ct++)
#pragma unroll
                for (int r = 0; r < 4; r++)
                    if (kt * 32 + ct * 16 + quad * 4 + r > qt * 64 + row_l)
                        sf[ct][r] = -1e30f;
        }
        // chain-cut online softmax (exp2 domain; log2e pre-folded into q):
        // per-lane max only in the common path; no DS shuffles.
        float t0 = fmaxf(sf[0][0], sf[0][1]), t1 = fmaxf(sf[0][2], sf[0][3]);
        float t2 = fmaxf(sf[1][0], sf[1][1]), t3 = fmaxf(sf[1][2], sf[1][3]);
        float mx_l = fmaxf(fmaxf(t0, t1), fmaxf(t2, t3));
        if (__any(mx_l > mrun + 8.0f)) {  // rare: full reduce + rescale
            float mx = fmaxf(mx_l, __shfl_xor(mx_l, 16, 64));
            mx = fmaxf(mx, __shfl_xor(mx, 32, 64));
            float mnew = fmaxf(mrun, mx);
            float al = fast_exp2(mrun - mnew);
            mrun = mnew;
            lrun *= al;
#pragma unroll
            for (int dt = 0; dt < 4; dt++)
#pragma unroll
                for (int r = 0; r < 4; r++) ot[dt][r] *= al;
        }
        float rs = 0.f;
#pragma unroll
        for (int ct = 0; ct < 2; ct++)
#pragma unroll
            for (int r = 0; r < 4; r++) {
                float p = fast_exp2(sf[ct][r] - mrun);  // bounded by 2^8
                sf[ct][r] = p;
                rs += p;
            }
        lrun += rs;  // per-lane partial; cross-quad reduce deferred to epilogue
        // P -> packed bf16 B-fragments for 16x16x16 (k=quad*4+j = C-layout)
        s16x4 bpr[2];
#pragma unroll
        for (int ct = 0; ct < 2; ct++) {
            uint2 u;
            u.x = cvtpk_bf16(sf[ct][0], sf[ct][1]);
            u.y = cvtpk_bf16(sf[ct][2], sf[ct][3]);
            bpr[ct] = __builtin_bit_cast(s16x4, u);
        }
        // Ot += V^T * P^T
        prio_hi();
#pragma unroll
        for (int dt = 0; dt < 4; dt++) {
#pragma unroll
            for (int ct = 0; ct < 2; ct++) {
                s16x4 av = *(const s16x4*)&Vt[g][cb][dt * 16 + l16][ct * 16 + quad * 4];
                ot[dt] = mfma_k16(av, bpr[ct], ot[dt]);
            }
        }
        prio_lo();
        if (pf) {  // write prefetched tile to the other buffer
            *(u16x8*)&Ks[g][1 - cb][kr][kc] = pk;
            *(u16x8*)&Vt[g][1 - cb][vr][vc] = pv;
        }
        __syncthreads();  // single barrier per tile
    }

    // deferred cross-quad sum reduce (once, instead of 2 shuffles per tile)
    lrun += __shfl_xor(lrun, 16, 64);
    lrun += __shfl_xor(lrun, 32, 64);

    // ---- cross-group merge (group 1 -> LDS, group 0 combines + writes) ----
    if (g == 1) {
        msm[row_l] = mrun;  // quads duplicate-write identical values: benign
        lsm[row_l] = lrun;
#pragma unroll
        for (int dt = 0; dt < 4; dt++)
            *(f32x4*)&Osm[row_l][dt * 16 + quad * 4] = ot[dt];
    }
    __syncthreads();
    if (g == 0) {
        float m1 = msm[row_l], l1 = lsm[row_l];
        float mmax = fmaxf(mrun, m1);
        float a0 = fast_exp2(mrun - mmax), a1 = fast_exp2(m1 - mmax);
        float inv = 1.0f / (a0 * lrun + a1 * l1);
        float s0 = a0 * inv, s1 = a1 * inv;
        size_t rowbase = ((size_t)b * 2048 + qt * 64 + row_l) * 1024 + h * 64;
#pragma unroll
        for (int dt = 0; dt < 4; dt++) {
            f32x4 o1 = *(const f32x4*)&Osm[row_l][dt * 16 + quad * 4];
            uint2 pkk;
            pkk.x = cvtpk_bf16(ot[dt][0] * s0 + o1[0] * s1,
                               ot[dt][1] * s0 + o1[1] * s1);
            pkk.y = cvtpk_bf16(ot[dt][2] * s0 + o1[2] * s1,
                               ot[dt][3] * s0 + o1[3] * s1);
            *(uint2*)&o[rowbase + dt * 16 + quad * 4] = pkk;
        }
    }
}

extern "C" void kernel_launch(void* const* d_in, const int* in_sizes, int n_in,
                              void* d_out, int out_size, void* d_ws, size_t ws_size,
                              hipStream_t stream) {
    const float* x = (const float*)d_in[0];       // [2,2048,1024]
    const float* gamma = (const float*)d_in[1];   // [1024]
    const float* w_qkv = (const float*)d_in[2];   // [1024,3072]
    const float* w_out = (const float*)d_in[3];   // [1024,1024]
    float* out = (float*)d_out;                   // [2,2048,1024] fp32
    char* ws = (char*)d_ws;

    unsigned short* xn = (unsigned short*)(ws);              // 8 MB (reused as ao)
    unsigned short* wtq = (unsigned short*)(ws + 8388608);   // 6 MB  [3072][1024]
    unsigned short* wto = (unsigned short*)(ws + 14680064);  // 2 MB  [1024][1024]
    unsigned short* qw = (unsigned short*)(ws + 16777216);   // 8 MB  [32][2048][64]
    unsigned short* kw = (unsigned short*)(ws + 25165824);   // 8 MB  [32][2048][64]
    unsigned short* vw = (unsigned short*)(ws + 33554432);   // 8 MB  [32][64][2048]
    unsigned short* ao = xn;                                 // reuse after QKV GEMM

    // zero-init out for split-K atomicAdd (graph-capturable; ordered on stream)
    hipMemsetAsync(out, 0, (size_t)4096 * 1024 * 4, stream);

    prep_k<<<8192, 256, 0, stream>>>(x, gamma, w_qkv, w_out, xn, wtq, wto);
    gemm_bt_k<1, 128, 1><<<dim3(24, 32), 256, 0, stream>>>(xn, wtq, nullptr, qw, kw, vw,
                                                           4096, 3072, 1024);
    attn_k<<<dim3(32, 32), 512, 0, stream>>>(qw, kw, vw, ao);
    // split-K=2: 1024 blocks = 4 blocks/CU (m97's proven overlap config);
    // 16 K-steps each; fp32 atomicAdd into the pre-zeroed out buffer.
    gemm_bt_k<0, 64, 2><<<dim3(8, 64, 2), 256, 0, stream>>>(ao, wto, out, nullptr,
                                                            nullptr, nullptr,
                                                            4096, 1024, 1024);
}

// Round 8
// 186.718 us; speedup vs baseline: 1.0942x; 1.0942x over previous
//
#include <hip/hip_runtime.h>
#include <hip/hip_bf16.h>

typedef __bf16 bf16x8 __attribute__((ext_vector_type(8)));
typedef short s16x4 __attribute__((ext_vector_type(4)));
typedef float f32x4 __attribute__((ext_vector_type(4)));
typedef unsigned short u16x8 __attribute__((ext_vector_type(8)));

#define MFMA_K32(a, b, c) __builtin_amdgcn_mfma_f32_16x16x32_bf16(a, b, c, 0, 0, 0)

// 16x16x16 bf16 MFMA; builtin exists only in device pass.
static __device__ __forceinline__ f32x4 mfma_k16(s16x4 a, s16x4 b, f32x4 c) {
#ifdef __HIP_DEVICE_COMPILE__
    return __builtin_amdgcn_mfma_f32_16x16x16bf16_1k(a, b, c, 0, 0, 0);
#else
    return c;
#endif
}

static __device__ __forceinline__ float fast_exp2(float x) {
#ifdef __HIP_DEVICE_COMPILE__
    return __builtin_amdgcn_exp2f(x);
#else
    return x;
#endif
}

static __device__ __forceinline__ void prio_hi() {
#ifdef __HIP_DEVICE_COMPILE__
    __builtin_amdgcn_s_setprio(1);
#endif
}
static __device__ __forceinline__ void prio_lo() {
#ifdef __HIP_DEVICE_COMPILE__
    __builtin_amdgcn_s_setprio(0);
#endif
}

// async global->LDS, 16B per lane; lds dest = wave-uniform base + lane*16
#define GLL16(gp, lp)                                              \
    __builtin_amdgcn_global_load_lds(                              \
        (const __attribute__((address_space(1))) void*)(gp),       \
        (__attribute__((address_space(3))) void*)(lp), 16, 0, 0)

// round-to-nearest-even fp32 -> bf16 (finite inputs only)
static __device__ __forceinline__ unsigned short f2bf(float f) {
    unsigned int u = __float_as_uint(f);
    u += 0x7fffu + ((u >> 16) & 1u);
    return (unsigned short)(u >> 16);
}

// packed fp32x2 -> bf16x2 (RNE) via gfx950 v_cvt_pk_bf16_f32 when available
static __device__ __forceinline__ unsigned int cvtpk_bf16(float lo, float hi) {
#if defined(__HIP_DEVICE_COMPILE__) && __has_builtin(__builtin_amdgcn_cvt_pk_bf16_f32)
    typedef __bf16 bf16x2 __attribute__((ext_vector_type(2)));
    bf16x2 r = __builtin_amdgcn_cvt_pk_bf16_f32(lo, hi);
    return __builtin_bit_cast(unsigned int, r);
#else
    return (unsigned int)f2bf(lo) | ((unsigned int)f2bf(hi) << 16);
#endif
}

#define LOG2E 1.44269504088896340736f

// ---------------------------------------------------------------------------
// Fused prep: transpose+cast w_qkv and w_out, rmsnorm x -> xn (bf16).
// bid < 3072: w_qkv tile; < 4096: w_out tile; else rmsnorm row (bid-4096).
// ---------------------------------------------------------------------------
__global__ __launch_bounds__(256) void prep_k(
    const float* __restrict__ x, const float* __restrict__ gamma,
    const float* __restrict__ w_qkv, const float* __restrict__ w_out,
    unsigned short* __restrict__ xn, unsigned short* __restrict__ wtq,
    unsigned short* __restrict__ wto) {
    __shared__ float sm[32][33];
    int bid = blockIdx.x, tid = threadIdx.x;
    if (bid < 4096) {  // transpose paths (block-uniform branch)
        const float* in;
        unsigned short* out;
        int R = 1024, C, bx, by;
        if (bid < 3072) { in = w_qkv; out = wtq; C = 3072; bx = bid % 96; by = bid / 96; }
        else { int b2 = bid - 3072; in = w_out; out = wto; C = 1024; bx = b2 % 32; by = b2 / 32; }
        int c0 = bx * 32, r0 = by * 32;
        int tr = tid >> 5, tc = tid & 31;
#pragma unroll
        for (int i = 0; i < 4; i++)
            sm[tr + i * 8][tc] = in[(size_t)(r0 + tr + i * 8) * C + c0 + tc];
        __syncthreads();
#pragma unroll
        for (int i = 0; i < 4; i++)
            out[(size_t)(c0 + tr + i * 8) * R + r0 + tc] = f2bf(sm[tc][tr + i * 8]);
    } else {  // rmsnorm
        int row = bid - 4096;
        const float* xr = x + (size_t)row * 1024;
        float4 v = *(const float4*)(xr + tid * 4);
        float ss = v.x * v.x + v.y * v.y + v.z * v.z + v.w * v.w;
#pragma unroll
        for (int off = 1; off < 64; off <<= 1) ss += __shfl_xor(ss, off, 64);
        if ((tid & 63) == 0) sm[0][tid >> 6] = ss;
        __syncthreads();
        float tot = sm[0][0] + sm[0][1] + sm[0][2] + sm[0][3];
        float f = 32.0f / fmaxf(sqrtf(tot), 1e-12f);  // sqrt(1024)=32
        float4 g = *(const float4*)(gamma + tid * 4);
        uint2 o;
        o.x = cvtpk_bf16(v.x * f * g.x, v.y * f * g.y);
        o.y = cvtpk_bf16(v.z * f * g.z, v.w * f * g.w);
        *(uint2*)(xn + (size_t)row * 1024 + tid * 4) = o;
    }
}

// ---------------------------------------------------------------------------
// GEMM (m97 structure): C[M,N] = A[M,K] * BT[N,K]^T, bf16 in, fp32 acc.
// BM x 128 tile, BK=32, global_load_lds width-16 staging into unpadded LDS.
// BM=128: 4 waves 2x2 (4x4 frags). BM=64: 4 waves 1x4 (4x2 frags).
// MODE 0: fp32 store (atomicAdd when KS>1). MODE 1: qkv epilogue.
// R5: BM=128 for gemm2 -> 1 block/CU, barrier drain exposed. Keep BM=64.
// R7: split-K=2 + atomicAdd + memset regressed total +16us (atomic RMW
// epilogue swamps the TLP gain at this size). KS=1 everywhere.
// ---------------------------------------------------------------------------
template <int MODE, int BM, int KS>
__global__ __launch_bounds__(256) void gemm_bt_k(
    const unsigned short* __restrict__ A, const unsigned short* __restrict__ BT,
    float* __restrict__ C, unsigned short* __restrict__ qw,
    unsigned short* __restrict__ kw, unsigned short* __restrict__ vw,
    int M, int N, int K) {
    constexpr int RT = 4;
    constexpr int CT = (BM == 128) ? 4 : 2;
    __shared__ unsigned short As[BM][32];
    __shared__ unsigned short Bs[128][32];
    int tid = threadIdx.x;
    int wave = tid >> 6, lane = tid & 63, quad = lane >> 4, l16 = lane & 15;
    int wrb, wcb;
    if constexpr (BM == 128) { wrb = (wave >> 1) * 64; wcb = (wave & 1) * 64; }
    else { wrb = 0; wcb = wave * 32; }
    int m0 = blockIdx.y * BM, n0 = blockIdx.x * 128;
    int k_beg = 0, k_end = K;
    if constexpr (KS > 1) {
        int kz = blockIdx.z;
        k_beg = kz * (K / KS);
        k_end = k_beg + K / KS;
    }
    int lrow = lane >> 2, lcol = (lane & 3) * 8;  // lane -> (row,col) in 16x32 chunk
    const unsigned short *Ag0, *Ag1 = nullptr;
    if constexpr (BM == 128) {
        Ag0 = A + (size_t)(m0 + wave * 32 + lrow) * K + lcol;
        Ag1 = A + (size_t)(m0 + wave * 32 + 16 + lrow) * K + lcol;
    } else {
        Ag0 = A + (size_t)(m0 + wave * 16 + lrow) * K + lcol;
    }
    const unsigned short* Bg0 = BT + (size_t)(n0 + wave * 32 + lrow) * K + lcol;
    const unsigned short* Bg1 = BT + (size_t)(n0 + wave * 32 + 16 + lrow) * K + lcol;
    f32x4 acc[RT][CT] = {};
    for (int k0 = k_beg; k0 < k_end; k0 += 32) {
        __syncthreads();  // prior ds_reads done before overwrite
        if constexpr (BM == 128) {
            GLL16(Ag0 + k0, &As[wave * 32][0]);
            GLL16(Ag1 + k0, &As[wave * 32 + 16][0]);
        } else {
            GLL16(Ag0 + k0, &As[wave * 16][0]);
        }
        GLL16(Bg0 + k0, &Bs[wave * 32][0]);
        GLL16(Bg1 + k0, &Bs[wave * 32 + 16][0]);
        __syncthreads();  // drains vmcnt: staging complete
        bf16x8 af[RT], bfr[CT];
#pragma unroll
        for (int t = 0; t < RT; t++)
            af[t] = *(const bf16x8*)&As[wrb + t * 16 + l16][quad * 8];
#pragma unroll
        for (int t = 0; t < CT; t++)
            bfr[t] = *(const bf16x8*)&Bs[wcb + t * 16 + l16][quad * 8];
#pragma unroll
        for (int rt = 0; rt < RT; rt++)
#pragma unroll
            for (int ct = 0; ct < CT; ct++)
                acc[rt][ct] = MFMA_K32(af[rt], bfr[ct], acc[rt][ct]);
    }
#pragma unroll
    for (int rt = 0; rt < RT; rt++) {
        int mb = m0 + wrb + rt * 16 + quad * 4;
        int b = mb >> 11, nn = mb & 2047;
#pragma unroll
        for (int ct = 0; ct < CT; ct++) {
            int col = n0 + wcb + ct * 16 + l16;
            if (MODE == 0) {
                if constexpr (KS > 1) {
#pragma unroll
                    for (int r = 0; r < 4; r++)
                        atomicAdd(&C[(size_t)(mb + r) * N + col], acc[rt][ct][r]);
                } else {
#pragma unroll
                    for (int r = 0; r < 4; r++)
                        C[(size_t)(mb + r) * N + col] = acc[rt][ct][r];
                }
            } else {
                int sec = col >> 10, ci = col & 1023;
                int hh = ci >> 6, dd = ci & 63;
                int bh = b * 16 + hh;
                if (sec == 0) {
#pragma unroll
                    for (int r = 0; r < 4; r++)
                        qw[((size_t)bh * 2048 + nn + r) * 64 + dd] =
                            f2bf(acc[rt][ct][r] * (0.125f * LOG2E));
                } else if (sec == 1) {
#pragma unroll
                    for (int r = 0; r < 4; r++)
                        kw[((size_t)bh * 2048 + nn + r) * 64 + dd] = f2bf(acc[rt][ct][r]);
                } else {
                    uint2 pk;
                    pk.x = cvtpk_bf16(acc[rt][ct][0], acc[rt][ct][1]);
                    pk.y = cvtpk_bf16(acc[rt][ct][2], acc[rt][ct][3]);
                    *(uint2*)&vw[((size_t)bh * 64 + dd) * 2048 + nn] = pk;
                }
            }
        }
    }
}

// ---------------------------------------------------------------------------
// Causal flash attention, key-split 8-wave blocks, KVBLK=64 (round 8).
// R6 validated the structure (chain-cut softmax, 46.7us). Per-block serial
// cost scales with TILE COUNT: each tile pays a full 8-wave barrier +
// prefetch branch + dbuf swap. KVBLK 32->64 halves barriers/iterations at
// the same per-key MFMA+exp2 work and doubles MFMA run length per sync.
// Group split is tile-granular: nTot = qt+1 64-key tiles; group 0 takes
// ceil(nTot/2), group 1 the rest; both run ceil(nTot/2) barrier-aligned
// iterations (group 1 idles last when nTot odd; act/pf wave-uniform).
// Only tile kt==qt masks. Empty group 1 (qt=0) benign in merge (a1->0).
// LDS 72KB/block -> still 2 blocks/CU. (512,4): 128-reg budget; transients
// ~doubled (est ~100 VGPR) - WRITE_SIZE is the spill tripwire.
// ---------------------------------------------------------------------------
__global__ __launch_bounds__(512, 4) void attn_k(
    const unsigned short* __restrict__ q, const unsigned short* __restrict__ k,
    const unsigned short* __restrict__ vt, unsigned short* __restrict__ o) {
    // LDS union: Ks[g][buf][key 64][d 64 pad 72] + Vt[g][buf][d 64][key 64 pad 72]
    // epilogue overlays Osm[64][68] f32 on the K region, msm/lsm on V region.
    __shared__ __align__(16) char smem[73728];
    typedef unsigned short ush;
    ush(*Ks)[2][64][72] = (ush(*)[2][64][72])smem;            // 36864 B
    ush(*Vt)[2][64][72] = (ush(*)[2][64][72])(smem + 36864);  // 36864 B
    float(*Osm)[68] = (float(*)[68])smem;                     // 17408 B (<= K region)
    float* msm = (float*)(smem + 36864);                      // 256 B (in V region)
    float* lsm = msm + 64;

    int bh = blockIdx.x;
    int qt = 31 - (int)blockIdx.y;  // heavy-first LPT order
    int tid = threadIdx.x, wave = tid >> 6, lane = tid & 63;
    int quad = lane >> 4, l16 = lane & 15;
    int g = wave >> 2, wq = wave & 3;
    int b = bh >> 4, h = bh & 15;
    const ush* qg = q + (size_t)bh * 2048 * 64;
    const ush* kg = k + (size_t)bh * 2048 * 64;
    const ush* vg = vt + (size_t)bh * 64 * 2048;

    // staging map: 256 threads/group stage a 64x64 tile in two u16x8 chunks.
    // K [key][64]: row=ti>>2, cols (ti&3)*8 and +32.  V [d][2048]: same map.
    int ti = wq * 64 + lane;
    int kr = ti >> 2, kc = (ti & 3) * 8;
    const ush* Kg = kg + (size_t)kr * 64 + kc;    // + kt*4096
    const ush* Vg = vg + (size_t)kr * 2048 + kc;  // + kt*64

    int row_l = wq * 16 + l16;    // local q row 0..63
    int q0w = qt * 64 + wq * 16;  // global q row base for this wave
    bf16x8 bq[2];                 // Q^T B-operand: [k=d=ks*32+quad*8+j][n=qrow=l16]
#pragma unroll
    for (int ks = 0; ks < 2; ks++)
        bq[ks] = *(const bf16x8*)&qg[(size_t)(q0w + l16) * 64 + ks * 32 + quad * 8];

    f32x4 ot[4] = {};                 // Ot C-layout: [d=dt*16+quad*4+r][qrow=l16]
    float mrun = -1e30f, lrun = 0.f;  // lrun is a PER-LANE partial (reduced at end)
    int nTot = qt + 1;                // 64-key tiles covering keys [0,(qt+1)*64)
    int nT0 = (nTot + 1) >> 1;        // group 0 tile count (= loop length L)
    int myN = g ? (nTot - nT0) : nT0;
    int kt0 = g ? nT0 : 0;
    int L = nT0;

    u16x8 pk0, pk1, pv0, pv1;  // prefetch registers (two chunks each)
    if (myN > 0) {             // preload first tile into buf 0
        pk0 = *(const u16x8*)(Kg + (size_t)kt0 * 4096);
        pk1 = *(const u16x8*)(Kg + (size_t)kt0 * 4096 + 32);
        pv0 = *(const u16x8*)(Vg + kt0 * 64);
        pv1 = *(const u16x8*)(Vg + kt0 * 64 + 32);
        *(u16x8*)&Ks[g][0][kr][kc] = pk0;
        *(u16x8*)&Ks[g][0][kr][kc + 32] = pk1;
        *(u16x8*)&Vt[g][0][kr][kc] = pv0;
        *(u16x8*)&Vt[g][0][kr][kc + 32] = pv1;
    }
    __syncthreads();

    for (int i = 0; i < L; i++) {
        int cb = i & 1, kt = kt0 + i;
        bool act = (i < myN);      // wave-uniform
        bool pf = (i + 1 < myN);   // wave-uniform
        if (pf) {  // issue next tile's global loads early
            pk0 = *(const u16x8*)(Kg + (size_t)(kt + 1) * 4096);
            pk1 = *(const u16x8*)(Kg + (size_t)(kt + 1) * 4096 + 32);
            pv0 = *(const u16x8*)(Vg + (kt + 1) * 64);
            pv1 = *(const u16x8*)(Vg + (kt + 1) * 64 + 32);
        }
        if (act) {
            // St[key=ct*16+quad*4+r][qrow=l16] = K . Q^T  (4 ct x 2 ks = 8 MFMA)
            f32x4 sf[4];
            prio_hi();
#pragma unroll
            for (int ct = 0; ct < 4; ct++) {
                bf16x8 ak0 = *(const bf16x8*)&Ks[g][cb][ct * 16 + l16][quad * 8];
                bf16x8 ak1 = *(const bf16x8*)&Ks[g][cb][ct * 16 + l16][32 + quad * 8];
                f32x4 s = {};
                s = MFMA_K32(ak0, bq[0], s);
                s = MFMA_K32(ak1, bq[1], s);
                sf[ct] = s;
            }
            prio_lo();
            if (kt == qt) {  // diagonal tile: causal mask (local indices)
#pragma unroll
                for (int ct = 0; ct < 4; ct++)
#pragma unroll
                    for (int r = 0; r < 4; r++)
                        if (ct * 16 + quad * 4 + r > row_l) sf[ct][r] = -1e30f;
            }
            // chain-cut online softmax: per-lane max; scalar ballot gates reduce
            float m01 = fmaxf(fmaxf(fmaxf(sf[0][0], sf[0][1]), fmaxf(sf[0][2], sf[0][3])),
                              fmaxf(fmaxf(sf[1][0], sf[1][1]), fmaxf(sf[1][2], sf[1][3])));
            float m23 = fmaxf(fmaxf(fmaxf(sf[2][0], sf[2][1]), fmaxf(sf[2][2], sf[2][3])),
                              fmaxf(fmaxf(sf[3][0], sf[3][1]), fmaxf(sf[3][2], sf[3][3])));
            float mx_l = fmaxf(m01, m23);
            if (__any(mx_l > mrun + 8.0f)) {  // rare: full reduce + rescale
                float mx = fmaxf(mx_l, __shfl_xor(mx_l, 16, 64));
                mx = fmaxf(mx, __shfl_xor(mx, 32, 64));
                float mnew = fmaxf(mrun, mx);
                float al = fast_exp2(mrun - mnew);
                mrun = mnew;
                lrun *= al;
#pragma unroll
                for (int dt = 0; dt < 4; dt++)
#pragma unroll
                    for (int r = 0; r < 4; r++) ot[dt][r] *= al;
            }
            float rs = 0.f;
#pragma unroll
            for (int ct = 0; ct < 4; ct++)
#pragma unroll
                for (int r = 0; r < 4; r++) {
                    float p = fast_exp2(sf[ct][r] - mrun);  // bounded by 2^8
                    sf[ct][r] = p;
                    rs += p;
                }
            lrun += rs;  // per-lane partial; cross-quad reduce in epilogue
            // P -> packed bf16 B-fragments for 16x16x16 (k=quad*4+j)
            s16x4 bpr[4];
#pragma unroll
            for (int ct = 0; ct < 4; ct++) {
                uint2 u;
                u.x = cvtpk_bf16(sf[ct][0], sf[ct][1]);
                u.y = cvtpk_bf16(sf[ct][2], sf[ct][3]);
                bpr[ct] = __builtin_bit_cast(s16x4, u);
            }
            // Ot += V^T * P^T  (4 dt x 4 ct = 16 MFMA)
            prio_hi();
#pragma unroll
            for (int dt = 0; dt < 4; dt++) {
#pragma unroll
                for (int ct = 0; ct < 4; ct++) {
                    s16x4 av = *(const s16x4*)&Vt[g][cb][dt * 16 + l16][ct * 16 + quad * 4];
                    ot[dt] = mfma_k16(av, bpr[ct], ot[dt]);
                }
            }
            prio_lo();
        }
        if (pf) {  // write prefetched tile to the other buffer
            *(u16x8*)&Ks[g][1 - cb][kr][kc] = pk0;
            *(u16x8*)&Ks[g][1 - cb][kr][kc + 32] = pk1;
            *(u16x8*)&Vt[g][1 - cb][kr][kc] = pv0;
            *(u16x8*)&Vt[g][1 - cb][kr][kc + 32] = pv1;
        }
        __syncthreads();  // single barrier per 64-key tile (was per 32)
    }

    // deferred cross-quad sum reduce (once)
    lrun += __shfl_xor(lrun, 16, 64);
    lrun += __shfl_xor(lrun, 32, 64);

    // ---- cross-group merge (group 1 -> LDS, group 0 combines + writes) ----
    if (g == 1) {
        msm[row_l] = mrun;  // quads duplicate-write identical values: benign
        lsm[row_l] = lrun;
#pragma unroll
        for (int dt = 0; dt < 4; dt++)
            *(f32x4*)&Osm[row_l][dt * 16 + quad * 4] = ot[dt];
    }
    __syncthreads();
    if (g == 0) {
        float m1 = msm[row_l], l1 = lsm[row_l];
        float mmax = fmaxf(mrun, m1);
        float a0 = fast_exp2(mrun - mmax), a1 = fast_exp2(m1 - mmax);
        float inv = 1.0f / (a0 * lrun + a1 * l1);
        float s0 = a0 * inv, s1 = a1 * inv;
        size_t rowbase = ((size_t)b * 2048 + qt * 64 + row_l) * 1024 + h * 64;
#pragma unroll
        for (int dt = 0; dt < 4; dt++) {
            f32x4 o1 = *(const f32x4*)&Osm[row_l][dt * 16 + quad * 4];
            uint2 pkk;
            pkk.x = cvtpk_bf16(ot[dt][0] * s0 + o1[0] * s1,
                               ot[dt][1] * s0 + o1[1] * s1);
            pkk.y = cvtpk_bf16(ot[dt][2] * s0 + o1[2] * s1,
                               ot[dt][3] * s0 + o1[3] * s1);
            *(uint2*)&o[rowbase + dt * 16 + quad * 4] = pkk;
        }
    }
}

extern "C" void kernel_launch(void* const* d_in, const int* in_sizes, int n_in,
                              void* d_out, int out_size, void* d_ws, size_t ws_size,
                              hipStream_t stream) {
    const float* x = (const float*)d_in[0];       // [2,2048,1024]
    const float* gamma = (const float*)d_in[1];   // [1024]
    const float* w_qkv = (const float*)d_in[2];   // [1024,3072]
    const float* w_out = (const float*)d_in[3];   // [1024,1024]
    float* out = (float*)d_out;                   // [2,2048,1024] fp32
    char* ws = (char*)d_ws;

    unsigned short* xn = (unsigned short*)(ws);              // 8 MB (reused as ao)
    unsigned short* wtq = (unsigned short*)(ws + 8388608);   // 6 MB  [3072][1024]
    unsigned short* wto = (unsigned short*)(ws + 14680064);  // 2 MB  [1024][1024]
    unsigned short* qw = (unsigned short*)(ws + 16777216);   // 8 MB  [32][2048][64]
    unsigned short* kw = (unsigned short*)(ws + 25165824);   // 8 MB  [32][2048][64]
    unsigned short* vw = (unsigned short*)(ws + 33554432);   // 8 MB  [32][64][2048]
    unsigned short* ao = xn;                                 // reuse after QKV GEMM

    prep_k<<<8192, 256, 0, stream>>>(x, gamma, w_qkv, w_out, xn, wtq, wto);
    gemm_bt_k<1, 128, 1><<<dim3(24, 32), 256, 0, stream>>>(xn, wtq, nullptr, qw, kw, vw,
                                                           4096, 3072, 1024);
    attn_k<<<dim3(32, 32), 512, 0, stream>>>(qw, kw, vw, ao);
    // KS=1 (R7: split-K atomic epilogue + memset cost more than the TLP gain)
    gemm_bt_k<0, 64, 1><<<dim3(8, 64), 256, 0, stream>>>(ao, wto, out, nullptr,
                                                         nullptr, nullptr,
                                                         4096, 1024, 1024);
}

// Round 9
// 185.468 us; speedup vs baseline: 1.1016x; 1.0067x over previous
//
#include <hip/hip_runtime.h>
#include <hip/hip_bf16.h>

typedef __bf16 bf16x8 __attribute__((ext_vector_type(8)));
typedef short s16x4 __attribute__((ext_vector_type(4)));
typedef float f32x4 __attribute__((ext_vector_type(4)));
typedef unsigned short u16x8 __attribute__((ext_vector_type(8)));

#define MFMA_K32(a, b, c) __builtin_amdgcn_mfma_f32_16x16x32_bf16(a, b, c, 0, 0, 0)

// 16x16x16 bf16 MFMA; builtin exists only in device pass.
static __device__ __forceinline__ f32x4 mfma_k16(s16x4 a, s16x4 b, f32x4 c) {
#ifdef __HIP_DEVICE_COMPILE__
    return __builtin_amdgcn_mfma_f32_16x16x16bf16_1k(a, b, c, 0, 0, 0);
#else
    return c;
#endif
}

static __device__ __forceinline__ float fast_exp2(float x) {
#ifdef __HIP_DEVICE_COMPILE__
    return __builtin_amdgcn_exp2f(x);
#else
    return x;
#endif
}

static __device__ __forceinline__ void prio_hi() {
#ifdef __HIP_DEVICE_COMPILE__
    __builtin_amdgcn_s_setprio(1);
#endif
}
static __device__ __forceinline__ void prio_lo() {
#ifdef __HIP_DEVICE_COMPILE__
    __builtin_amdgcn_s_setprio(0);
#endif
}

// async global->LDS, 16B per lane; lds dest = wave-uniform base + lane*16
#define GLL16(gp, lp)                                              \
    __builtin_amdgcn_global_load_lds(                              \
        (const __attribute__((address_space(1))) void*)(gp),       \
        (__attribute__((address_space(3))) void*)(lp), 16, 0, 0)

// round-to-nearest-even fp32 -> bf16 (finite inputs only)
static __device__ __forceinline__ unsigned short f2bf(float f) {
    unsigned int u = __float_as_uint(f);
    u += 0x7fffu + ((u >> 16) & 1u);
    return (unsigned short)(u >> 16);
}

// packed fp32x2 -> bf16x2 (RNE) via gfx950 v_cvt_pk_bf16_f32 when available
static __device__ __forceinline__ unsigned int cvtpk_bf16(float lo, float hi) {
#if defined(__HIP_DEVICE_COMPILE__) && __has_builtin(__builtin_amdgcn_cvt_pk_bf16_f32)
    typedef __bf16 bf16x2 __attribute__((ext_vector_type(2)));
    bf16x2 r = __builtin_amdgcn_cvt_pk_bf16_f32(lo, hi);
    return __builtin_bit_cast(unsigned int, r);
#else
    return (unsigned int)f2bf(lo) | ((unsigned int)f2bf(hi) << 16);
#endif
}

#define LOG2E 1.44269504088896340736f

// ---------------------------------------------------------------------------
// Fused prep: transpose+cast w_qkv and w_out, rmsnorm x -> xn (bf16).
// bid < 3072: w_qkv tile; < 4096: w_out tile; else rmsnorm row (bid-4096).
// ---------------------------------------------------------------------------
__global__ __launch_bounds__(256) void prep_k(
    const float* __restrict__ x, const float* __restrict__ gamma,
    const float* __restrict__ w_qkv, const float* __restrict__ w_out,
    unsigned short* __restrict__ xn, unsigned short* __restrict__ wtq,
    unsigned short* __restrict__ wto) {
    __shared__ float sm[32][33];
    int bid = blockIdx.x, tid = threadIdx.x;
    if (bid < 4096) {  // transpose paths (block-uniform branch)
        const float* in;
        unsigned short* out;
        int R = 1024, C, bx, by;
        if (bid < 3072) { in = w_qkv; out = wtq; C = 3072; bx = bid % 96; by = bid / 96; }
        else { int b2 = bid - 3072; in = w_out; out = wto; C = 1024; bx = b2 % 32; by = b2 / 32; }
        int c0 = bx * 32, r0 = by * 32;
        int tr = tid >> 5, tc = tid & 31;
#pragma unroll
        for (int i = 0; i < 4; i++)
            sm[tr + i * 8][tc] = in[(size_t)(r0 + tr + i * 8) * C + c0 + tc];
        __syncthreads();
#pragma unroll
        for (int i = 0; i < 4; i++)
            out[(size_t)(c0 + tr + i * 8) * R + r0 + tc] = f2bf(sm[tc][tr + i * 8]);
    } else {  // rmsnorm
        int row = bid - 4096;
        const float* xr = x + (size_t)row * 1024;
        float4 v = *(const float4*)(xr + tid * 4);
        float ss = v.x * v.x + v.y * v.y + v.z * v.z + v.w * v.w;
#pragma unroll
        for (int off = 1; off < 64; off <<= 1) ss += __shfl_xor(ss, off, 64);
        if ((tid & 63) == 0) sm[0][tid >> 6] = ss;
        __syncthreads();
        float tot = sm[0][0] + sm[0][1] + sm[0][2] + sm[0][3];
        float f = 32.0f / fmaxf(sqrtf(tot), 1e-12f);  // sqrt(1024)=32
        float4 g = *(const float4*)(gamma + tid * 4);
        uint2 o;
        o.x = cvtpk_bf16(v.x * f * g.x, v.y * f * g.y);
        o.y = cvtpk_bf16(v.z * f * g.z, v.w * f * g.w);
        *(uint2*)(xn + (size_t)row * 1024 + tid * 4) = o;
    }
}

// ---------------------------------------------------------------------------
// GEMM: C[M,N] = A[M,K] * BT[N,K]^T, bf16 in, fp32 acc.  Round-9 structure:
// BK=64 (halves barrier count vs BK=32: 16 steps at K=1024) + XOR-swizzled
// LDS to kill the 8-way ds_read bank conflict (3.15M cycles/dispatch at R8).
// gll16 writes LDS linearly (can't scatter, m104), so the swizzle is applied
// on BOTH sides per rule #21: the global SOURCE column chunk is pre-swizzled
// (lane reads chunk (lane&7)^(lane>>3)) and the ds_read applies the same XOR
// ((kk*4+quad)^(l16&7)). Lanes then cover all 8 16B slots of a row stripe ->
// 2 lanes/bank-group = conflict-free (m136). LDS 32KB/block -> 4 blocks/CU.
// BM=128: 4 waves 2x2 (64x64/wave, 32 MFMA/step). BM=64: 4 waves 1x4.
// MODE 0: fp32 store. MODE 1: qkv epilogue (q scaled into exp2 domain;
// k [bh][n][d]; v transposed to [bh][d][n]).
// R5: BM=128 for gemm2 -> 1 block/CU, drain exposed; keep BM=64 there.
// R7: split-K atomic epilogue regressed; KS removed.
// ---------------------------------------------------------------------------
template <int MODE, int BM>
__global__ __launch_bounds__(256) void gemm_bt_k(
    const unsigned short* __restrict__ A, const unsigned short* __restrict__ BT,
    float* __restrict__ C, unsigned short* __restrict__ qw,
    unsigned short* __restrict__ kw, unsigned short* __restrict__ vw,
    int M, int N, int K) {
    constexpr int RT = 4;
    constexpr int CT = (BM == 128) ? 4 : 2;
    constexpr int ACH = BM / 32;  // A staging chunks per wave (8 rows each)
    __shared__ unsigned short As[BM][64];
    __shared__ unsigned short Bs[128][64];
    int tid = threadIdx.x;
    int wave = tid >> 6, lane = tid & 63, quad = lane >> 4, l16 = lane & 15;
    int wrb, wcb;
    if constexpr (BM == 128) { wrb = (wave >> 1) * 64; wcb = (wave & 1) * 64; }
    else { wrb = 0; wcb = wave * 32; }
    int m0 = blockIdx.y * BM, n0 = blockIdx.x * 128;
    // staging map: lane -> (row lrow, swizzled col chunk) of an 8x64 stripe
    int lrow = lane >> 3;
    int lcol = (((lane & 7) ^ (lane >> 3)) & 7) * 8;  // pre-swizzled source col
    const unsigned short* Ag[ACH];
#pragma unroll
    for (int c = 0; c < ACH; c++)
        Ag[c] = A + (size_t)(m0 + wave * (BM / 4) + c * 8 + lrow) * K + lcol;
    const unsigned short* Bg[4];
#pragma unroll
    for (int c = 0; c < 4; c++)
        Bg[c] = BT + (size_t)(n0 + wave * 32 + c * 8 + lrow) * K + lcol;
    f32x4 acc[RT][CT] = {};
    for (int k0 = 0; k0 < K; k0 += 64) {
        __syncthreads();  // prior ds_reads done before overwrite
#pragma unroll
        for (int c = 0; c < ACH; c++)
            GLL16(Ag[c] + k0, &As[wave * (BM / 4) + c * 8][0]);
#pragma unroll
        for (int c = 0; c < 4; c++)
            GLL16(Bg[c] + k0, &Bs[wave * 32 + c * 8][0]);
        __syncthreads();  // drains vmcnt: staging complete
#pragma unroll
        for (int kk = 0; kk < 2; kk++) {
            bf16x8 af[RT], bfr[CT];
#pragma unroll
            for (int t = 0; t < RT; t++)
                af[t] = *(const bf16x8*)
                    &As[wrb + t * 16 + l16][(((kk * 4 + quad) ^ (l16 & 7)) * 8)];
#pragma unroll
            for (int t = 0; t < CT; t++)
                bfr[t] = *(const bf16x8*)
                    &Bs[wcb + t * 16 + l16][(((kk * 4 + quad) ^ (l16 & 7)) * 8)];
#pragma unroll
            for (int rt = 0; rt < RT; rt++)
#pragma unroll
                for (int ct = 0; ct < CT; ct++)
                    acc[rt][ct] = MFMA_K32(af[rt], bfr[ct], acc[rt][ct]);
        }
    }
#pragma unroll
    for (int rt = 0; rt < RT; rt++) {
        int mb = m0 + wrb + rt * 16 + quad * 4;
        int b = mb >> 11, nn = mb & 2047;
#pragma unroll
        for (int ct = 0; ct < CT; ct++) {
            int col = n0 + wcb + ct * 16 + l16;
            if (MODE == 0) {
#pragma unroll
                for (int r = 0; r < 4; r++)
                    C[(size_t)(mb + r) * N + col] = acc[rt][ct][r];
            } else {
                int sec = col >> 10, ci = col & 1023;
                int hh = ci >> 6, dd = ci & 63;
                int bh = b * 16 + hh;
                if (sec == 0) {
#pragma unroll
                    for (int r = 0; r < 4; r++)
                        qw[((size_t)bh * 2048 + nn + r) * 64 + dd] =
                            f2bf(acc[rt][ct][r] * (0.125f * LOG2E));
                } else if (sec == 1) {
#pragma unroll
                    for (int r = 0; r < 4; r++)
                        kw[((size_t)bh * 2048 + nn + r) * 64 + dd] = f2bf(acc[rt][ct][r]);
                } else {
                    uint2 pk;
                    pk.x = cvtpk_bf16(acc[rt][ct][0], acc[rt][ct][1]);
                    pk.y = cvtpk_bf16(acc[rt][ct][2], acc[rt][ct][3]);
                    *(uint2*)&vw[((size_t)bh * 64 + dd) * 2048 + nn] = pk;
                }
            }
        }
    }
}

// ---------------------------------------------------------------------------
// Causal flash attention, key-split 8-wave blocks (R6 structure, EXACT).
// R8 post-mortem: KVBLK=64 cut residency 4->2 blocks/CU (LDS 73KB) and
// raised conflicts; 46.7 -> 50.1. Reverted. R6 = proven 46.7us: chain-cut
// softmax (per-lane max; scalar __any ballot gates the rare reduce+rescale;
// P bounded by 2^8, T13), per-lane lrun reduced once in epilogue, KVBLK=32,
// 1 barrier/tile, dbuf + reg prefetch. Groups of 4 waves split the key
// range; merge via LDS (fully-masked rows killed by a1->0).
// (512,4): 128-reg cap; VGPR 40 -> 4 blocks/CU (LDS 38.9KB x 4 fits).
// ---------------------------------------------------------------------------
__global__ __launch_bounds__(512, 4) void attn_k(
    const unsigned short* __restrict__ q, const unsigned short* __restrict__ k,
    const unsigned short* __restrict__ vt, unsigned short* __restrict__ o) {
    // LDS union: [group][buf] K tiles (32x64, pad 72) + V tiles (64x32, pad 40);
    // epilogue overlays Osm[64][68] f32 on the K region, msm/lsm on V region.
    __shared__ __align__(16) char smem[38912];
    typedef unsigned short ush;
    ush(*Ks)[2][32][72] = (ush(*)[2][32][72])smem;            // 18432 B
    ush(*Vt)[2][64][40] = (ush(*)[2][64][40])(smem + 18432);  // 20480 B
    float(*Osm)[68] = (float(*)[68])smem;                     // 17408 B (<= K region)
    float* msm = (float*)(smem + 18432);                      // 256 B (in V region)
    float* lsm = msm + 64;

    int bh = blockIdx.x;
    int qt = 31 - (int)blockIdx.y;  // heavy-first LPT order
    int tid = threadIdx.x, wave = tid >> 6, lane = tid & 63;
    int quad = lane >> 4, l16 = lane & 15;
    int g = wave >> 2, wq = wave & 3;
    int b = bh >> 4, h = bh & 15;
    const ush* qg = q + (size_t)bh * 2048 * 64;
    const ush* kg = k + (size_t)bh * 2048 * 64;
    const ush* vg = vt + (size_t)bh * 64 * 2048;

    // staging map: 256 threads/group; K: 32 rows x 64 cols; V: 64 d x 32 keys
    int ti = wq * 64 + lane;
    int kr = ti >> 3, kc = (ti & 7) * 8;
    int vr = ti >> 2, vc = (ti & 3) * 8;
    const ush* Kg = kg + (size_t)kr * 64 + kc;
    const ush* Vg = vg + (size_t)vr * 2048 + vc;

    int row_l = wq * 16 + l16;    // local q row 0..63
    int q0w = qt * 64 + wq * 16;  // global q row base for this wave
    bf16x8 bq[2];                 // Q^T B-operand: [k=d=ks*32+quad*8+j][n=qrow=l16]
#pragma unroll
    for (int ks = 0; ks < 2; ks++)
        bq[ks] = *(const bf16x8*)&qg[(size_t)(q0w + l16) * 64 + ks * 32 + quad * 8];

    f32x4 ot[4] = {};                 // Ot C-layout: [d=dt*16+quad*4+r][qrow=l16]
    float mrun = -1e30f, lrun = 0.f;  // lrun is a PER-LANE partial (reduced at end)
    int nT = qt + 1;                  // tiles per group (equal for both groups)
    int kt0 = g ? (qt + 1) : 0;

    u16x8 pk, pv;  // prefetch registers
    // preload first tile into buf 0
    pk = *(const u16x8*)(Kg + (size_t)kt0 * 2048);
    pv = *(const u16x8*)(Vg + kt0 * 32);
    *(u16x8*)&Ks[g][0][kr][kc] = pk;
    *(u16x8*)&Vt[g][0][vr][vc] = pv;
    __syncthreads();

    for (int i = 0; i < nT; i++) {
        int cb = i & 1, kt = kt0 + i;
        bool pf = (i + 1 < nT);
        if (pf) {  // issue next tile's global loads early (wave-uniform branch)
            pk = *(const u16x8*)(Kg + (size_t)(kt + 1) * 2048);
            pv = *(const u16x8*)(Vg + (kt + 1) * 32);
        }
        // St[key=ct*16+quad*4+r][qrow=l16] = K . Q^T
        f32x4 sf[2];
        prio_hi();
#pragma unroll
        for (int ct = 0; ct < 2; ct++) {
            bf16x8 ak0 = *(const bf16x8*)&Ks[g][cb][ct * 16 + l16][quad * 8];
            bf16x8 ak1 = *(const bf16x8*)&Ks[g][cb][ct * 16 + l16][32 + quad * 8];
            f32x4 s = {};
            s = MFMA_K32(ak0, bq[0], s);
            s = MFMA_K32(ak1, bq[1], s);
            sf[ct] = s;
        }
        prio_lo();
        if (kt >= 2 * qt) {  // tiles that can touch the diagonal
#pragma unroll
            for (int ct = 0; ct < 2; ct++)
#pragma unroll
                for (int r = 0; r < 4; r++)
                    if (kt * 32 + ct * 16 + quad * 4 + r > qt * 64 + row_l)
                        sf[ct][r] = -1e30f;
        }
        // chain-cut online softmax (exp2 domain; log2e pre-folded into q):
        // per-lane max only in the common path; no DS shuffles.
        float t0 = fmaxf(sf[0][0], sf[0][1]), t1 = fmaxf(sf[0][2], sf[0][3]);
        float t2 = fmaxf(sf[1][0], sf[1][1]), t3 = fmaxf(sf[1][2], sf[1][3]);
        float mx_l = fmaxf(fmaxf(t0, t1), fmaxf(t2, t3));
        if (__any(mx_l > mrun + 8.0f)) {  // rare: full reduce + rescale
            float mx = fmaxf(mx_l, __shfl_xor(mx_l, 16, 64));
            mx = fmaxf(mx, __shfl_xor(mx, 32, 64));
            float mnew = fmaxf(mrun, mx);
            float al = fast_exp2(mrun - mnew);
            mrun = mnew;
            lrun *= al;
#pragma unroll
            for (int dt = 0; dt < 4; dt++)
#pragma unroll
                for (int r = 0; r < 4; r++) ot[dt][r] *= al;
        }
        float rs = 0.f;
#pragma unroll
        for (int ct = 0; ct < 2; ct++)
#pragma unroll
            for (int r = 0; r < 4; r++) {
                float p = fast_exp2(sf[ct][r] - mrun);  // bounded by 2^8
                sf[ct][r] = p;
                rs += p;
            }
        lrun += rs;  // per-lane partial; cross-quad reduce deferred to epilogue
        // P -> packed bf16 B-fragments for 16x16x16 (k=quad*4+j = C-layout)
        s16x4 bpr[2];
#pragma unroll
        for (int ct = 0; ct < 2; ct++) {
            uint2 u;
            u.x = cvtpk_bf16(sf[ct][0], sf[ct][1]);
            u.y = cvtpk_bf16(sf[ct][2], sf[ct][3]);
            bpr[ct] = __builtin_bit_cast(s16x4, u);
        }
        // Ot += V^T * P^T
        prio_hi();
#pragma unroll
        for (int dt = 0; dt < 4; dt++) {
#pragma unroll
            for (int ct = 0; ct < 2; ct++) {
                s16x4 av = *(const s16x4*)&Vt[g][cb][dt * 16 + l16][ct * 16 + quad * 4];
                ot[dt] = mfma_k16(av, bpr[ct], ot[dt]);
            }
        }
        prio_lo();
        if (pf) {  // write prefetched tile to the other buffer
            *(u16x8*)&Ks[g][1 - cb][kr][kc] = pk;
            *(u16x8*)&Vt[g][1 - cb][vr][vc] = pv;
        }
        __syncthreads();  // single barrier per tile
    }

    // deferred cross-quad sum reduce (once, instead of 2 shuffles per tile)
    lrun += __shfl_xor(lrun, 16, 64);
    lrun += __shfl_xor(lrun, 32, 64);

    // ---- cross-group merge (group 1 -> LDS, group 0 combines + writes) ----
    if (g == 1) {
        msm[row_l] = mrun;  // quads duplicate-write identical values: benign
        lsm[row_l] = lrun;
#pragma unroll
        for (int dt = 0; dt < 4; dt++)
            *(f32x4*)&Osm[row_l][dt * 16 + quad * 4] = ot[dt];
    }
    __syncthreads();
    if (g == 0) {
        float m1 = msm[row_l], l1 = lsm[row_l];
        float mmax = fmaxf(mrun, m1);
        float a0 = fast_exp2(mrun - mmax), a1 = fast_exp2(m1 - mmax);
        float inv = 1.0f / (a0 * lrun + a1 * l1);
        float s0 = a0 * inv, s1 = a1 * inv;
        size_t rowbase = ((size_t)b * 2048 + qt * 64 + row_l) * 1024 + h * 64;
#pragma unroll
        for (int dt = 0; dt < 4; dt++) {
            f32x4 o1 = *(const f32x4*)&Osm[row_l][dt * 16 + quad * 4];
            uint2 pkk;
            pkk.x = cvtpk_bf16(ot[dt][0] * s0 + o1[0] * s1,
                               ot[dt][1] * s0 + o1[1] * s1);
            pkk.y = cvtpk_bf16(ot[dt][2] * s0 + o1[2] * s1,
                               ot[dt][3] * s0 + o1[3] * s1);
            *(uint2*)&o[rowbase + dt * 16 + quad * 4] = pkk;
        }
    }
}

extern "C" void kernel_launch(void* const* d_in, const int* in_sizes, int n_in,
                              void* d_out, int out_size, void* d_ws, size_t ws_size,
                              hipStream_t stream) {
    const float* x = (const float*)d_in[0];       // [2,2048,1024]
    const float* gamma = (const float*)d_in[1];   // [1024]
    const float* w_qkv = (const float*)d_in[2];   // [1024,3072]
    const float* w_out = (const float*)d_in[3];   // [1024,1024]
    float* out = (float*)d_out;                   // [2,2048,1024] fp32
    char* ws = (char*)d_ws;

    unsigned short* xn = (unsigned short*)(ws);              // 8 MB (reused as ao)
    unsigned short* wtq = (unsigned short*)(ws + 8388608);   // 6 MB  [3072][1024]
    unsigned short* wto = (unsigned short*)(ws + 14680064);  // 2 MB  [1024][1024]
    unsigned short* qw = (unsigned short*)(ws + 16777216);   // 8 MB  [32][2048][64]
    unsigned short* kw = (unsigned short*)(ws + 25165824);   // 8 MB  [32][2048][64]
    unsigned short* vw = (unsigned short*)(ws + 33554432);   // 8 MB  [32][64][2048]
    unsigned short* ao = xn;                                 // reuse after QKV GEMM

    prep_k<<<8192, 256, 0, stream>>>(x, gamma, w_qkv, w_out, xn, wtq, wto);
    gemm_bt_k<1, 128><<<dim3(24, 32), 256, 0, stream>>>(xn, wtq, nullptr, qw, kw, vw,
                                                        4096, 3072, 1024);
    attn_k<<<dim3(32, 32), 512, 0, stream>>>(qw, kw, vw, ao);
    gemm_bt_k<0, 64><<<dim3(8, 64), 256, 0, stream>>>(ao, wto, out, nullptr, nullptr,
                                                      nullptr, 4096, 1024, 1024);
}